// Round 6
// baseline (354.868 us; speedup 1.0000x reference)
//
#include <hip/hip_runtime.h>
#include <hip/hip_bf16.h>

// Problem constants (match reference file)
constexpr int K    = 8192;
constexpr int N4   = 6144;    // int4 rows
constexpr int N8   = 2048;    // uint8 rows
constexpr int NT   = N4 + N8; // 8192 output columns
constexpr int NG   = K / 128; // 64 groups per int4 row
constexpr int KS   = 4096;    // K per split (split-K x2)

constexpr int P4_ROWD = K / 8;            // 1024 dwords per packed int4 row
constexpr int P8_ROWD = K / 4;            // 2048 dwords per packed uint8 row
constexpr int P4_DWORDS = N4 * P4_ROWD;   // 6,291,456
constexpr int P8_DWORDS = N8 * P8_ROWD;   // 4,194,304

typedef short  short8  __attribute__((ext_vector_type(8)));
typedef float  floatx4 __attribute__((ext_vector_type(4)));

__device__ inline short f2bf(float f) {
    __hip_bfloat16 h = __float2bfloat16(f);   // RNE
    return __builtin_bit_cast(short, h);
}

// ---------------------------------------------------------------------------
// Prep: x2bf = bf16(x/awq) in MFMA A-fragment order; fwd = inv(inv_perm);
// out pre-filled with bias (GEMV accumulates atomically).
// ---------------------------------------------------------------------------
__global__ void prep_kernel(const float* __restrict__ x,
                            const float* __restrict__ awq,
                            const int*   __restrict__ inv_perm,
                            const float* __restrict__ bias,
                            short* __restrict__ x2bf,
                            int*   __restrict__ fwd,
                            float* __restrict__ out) {
    const int tid  = blockIdx.x * blockDim.x + threadIdx.x;   // 0..131071
    const int c    = tid >> 9;
    const int rem  = tid & 511;
    const int lane = rem >> 3;
    const int j    = rem & 7;
    const int m    = lane & 15;
    const int k    = c * 32 + (lane >> 4) * 8 + j;
    x2bf[tid] = f2bf(x[m * K + k] / awq[k]);
    if (tid < NT) fwd[inv_perm[tid]] = tid;
    out[tid] = bias[tid & (NT - 1)];          // out = bias, pre-perm indexed
}

// ---------------------------------------------------------------------------
// Repack: int32-stored weights -> nibble/byte-packed, in the exact lane order
// the GEMV's MFMA B-fragment consumes. 268 MB sequential read, 42 MB write —
// same traffic shape as the harness fills (which run at 6.9 TB/s). This is
// both the bytes-reduction (6.7x for w4, 4x for w8) and the clean probe of
// the streaming-read ceiling that rounds 0-4 never isolated.
//   p4[r][G*16 + q*4 + c]        = 8 nibbles, kk = G*128 + c*32 + q*8 + j
//   p8[r][G*32 + q*8 + c*2 + h]  = 4 bytes,   kk = G*128 + c*32 + q*8 + h*4 + j
// Each wave reads a dense 1-2 KB window (permuted within), writes 256 B dense.
// ---------------------------------------------------------------------------
__global__ __launch_bounds__(256)
void repack_kernel(const int* __restrict__ w4, const int* __restrict__ w8,
                   unsigned int* __restrict__ p4, unsigned int* __restrict__ p8) {
    const int t = blockIdx.x * 256 + threadIdx.x;
    if (t < P4_DWORDS) {
        const int r   = t >> 10;            // P4_ROWD = 1024
        const int d   = t & 1023;
        const int G   = d >> 4;
        const int rem = d & 15;
        const int q   = rem >> 2;
        const int c   = rem & 3;
        const int kk  = G * 128 + c * 32 + q * 8;
        const int* src = w4 + (size_t)r * K + kk;
        const int4 a = *(const int4*)src;
        const int4 b = *(const int4*)(src + 4);
        unsigned int v = (unsigned int)a.x        | ((unsigned int)a.y << 4)
                       | ((unsigned int)a.z << 8) | ((unsigned int)a.w << 12)
                       | ((unsigned int)b.x << 16)| ((unsigned int)b.y << 20)
                       | ((unsigned int)b.z << 24)| ((unsigned int)b.w << 28);
        p4[t] = v;
    } else {
        const int t8  = t - P4_DWORDS;      // < P8_DWORDS (grid sized exactly)
        const int r   = t8 >> 11;           // P8_ROWD = 2048
        const int d   = t8 & 2047;
        const int G   = d >> 5;
        const int rem = d & 31;
        const int q   = rem >> 3;
        const int c   = (rem >> 1) & 3;
        const int h   = rem & 1;
        const int kk  = G * 128 + c * 32 + q * 8 + h * 4;
        const int4 a = *(const int4*)(w8 + (size_t)r * K + kk);
        unsigned int v = (unsigned int)(a.x & 255)
                       | ((unsigned int)(a.y & 255) << 8)
                       | ((unsigned int)(a.z & 255) << 16)
                       | ((unsigned int)(a.w & 255) << 24);
        p8[t8] = v;
    }
}

// ---------------------------------------------------------------------------
// Packed split-K x2 MFMA GEMV. Block = 4 waves = 16-row tile x half of K;
// wave w owns 8 groups of 128 k (absolute group base G0 = split*32 + w*8).
// Per group per lane: ONE uint4 (w4: 4 chunks x 8 nibbles) or TWO uint4
// (w8: 4 chunks x 8 bytes) + 4 x-fragments. Packed arrays are 42 MB and
// freshly written -> L2/L3 resident; every 64B line is fully wave-consumed.
// Dequant identical math to rounds 0-4 (passing): w4: e*s - 8s; w8: e - 128
// exact in bf16, s8 + 8*s*sum_x correction folded, applied in epilogue.
// 2-stage A/B register pipeline with sched_barrier pins (round-3 proven).
// Epilogue: 4KB LDS cross-wave reduce + s8/perm + atomicAdd (bias pre-seeded).
// ---------------------------------------------------------------------------
__global__ __launch_bounds__(256)
void qgemv_kernel(const short* __restrict__ xf,
                  const unsigned int* __restrict__ p4,
                  const float* __restrict__ s4,
                  const unsigned int* __restrict__ p8,
                  const float* __restrict__ s8,
                  const int*   __restrict__ fwd,
                  float* __restrict__ out) {
    __shared__ float lds[4 * 256];

    const int t     = threadIdx.x;
    const int lane  = t & 63;
    const int w     = t >> 6;              // wave 0..3
    const int tile  = blockIdx.x >> 1;
    const int split = blockIdx.x & 1;
    const int nb    = tile * 16;           // tile base row
    const int i     = lane & 15;
    const int q     = lane >> 4;
    const int row   = nb + i;
    const bool is4  = (nb < N4);
    const int row8  = is4 ? 0 : (row - N4);
    const int G0    = split * 32 + w * 8;  // absolute group base

    const unsigned int* wp4 = p4 + (size_t)row  * P4_ROWD + G0 * 16 + q * 4;
    const unsigned int* wp8 = p8 + (size_t)row8 * P8_ROWD + G0 * 32 + q * 8;
    const short* xw = xf + (size_t)G0 * 4 * 512 + lane * 8;   // + (g*4+c)*512
    const float* sp = is4 ? (s4 + (size_t)row * NG + G0) : nullptr;

    floatx4 acc = {0.f, 0.f, 0.f, 0.f};

    uint4  w4A, w4B;          // w4: 4 dwords = 4 chunks
    uint4  w8A[2], w8B[2];    // w8: 8 dwords = 4 chunks x {lo,hi}
    short8 xA[4], xB[4];
    float  sA = 0.f, sB = 0.f;

    auto loadg = [&](int g, uint4& wv4, uint4* wv8, short8* xv, float& s) {
        if (is4) {
            wv4 = *(const uint4*)(wp4 + (size_t)g * 16);
            s   = sp[g];
        } else {
            wv8[0] = *(const uint4*)(wp8 + (size_t)g * 32);
            wv8[1] = *(const uint4*)(wp8 + (size_t)g * 32 + 4);
        }
        #pragma unroll
        for (int c = 0; c < 4; ++c)
            xv[c] = *(const short8*)(xw + (size_t)(g * 4 + c) * 512);
    };

    auto compg = [&](const uint4& wv4, const uint4* wv8, const short8* xv,
                     float s) {
        if (is4) {
            const float sc = s, sb = -8.f * s;
            #pragma unroll
            for (int c = 0; c < 4; ++c) {
                const unsigned int v = wv4[c];
                short8 bf;
                #pragma unroll
                for (int j = 0; j < 8; ++j)
                    bf[j] = f2bf((float)((v >> (4 * j)) & 15u) * sc + sb);
                acc = __builtin_amdgcn_mfma_f32_16x16x32_bf16(xv[c], bf, acc,
                                                              0, 0, 0);
            }
        } else {
            #pragma unroll
            for (int c = 0; c < 4; ++c) {
                const unsigned int lo = (c < 2 ? wv8[0] : wv8[1])[(c & 1) * 2];
                const unsigned int hi = (c < 2 ? wv8[0] : wv8[1])[(c & 1) * 2 + 1];
                short8 bf;
                #pragma unroll
                for (int j = 0; j < 4; ++j) {
                    bf[j]     = f2bf((float)((lo >> (8 * j)) & 255u) - 128.f);
                    bf[4 + j] = f2bf((float)((hi >> (8 * j)) & 255u) - 128.f);
                }
                acc = __builtin_amdgcn_mfma_f32_16x16x32_bf16(xv[c], bf, acc,
                                                              0, 0, 0);
            }
        }
    };

    // 8 groups, 2-stage A/B register pipeline, peeled tail.
    loadg(0, w4A, w8A, xA, sA);
    __builtin_amdgcn_sched_barrier(0);
    #pragma unroll 1
    for (int g = 0; g < 6; g += 2) {
        loadg(g + 1, w4B, w8B, xB, sB);
        __builtin_amdgcn_sched_barrier(0);
        compg(w4A, w8A, xA, sA);
        loadg(g + 2, w4A, w8A, xA, sA);
        __builtin_amdgcn_sched_barrier(0);
        compg(w4B, w8B, xB, sB);
    }
    loadg(7, w4B, w8B, xB, sB);
    __builtin_amdgcn_sched_barrier(0);
    compg(w4A, w8A, xA, sA);
    compg(w4B, w8B, xB, sB);

    // ---- cross-wave reduce + fused scale/perm atomic writeout ----
    #pragma unroll
    for (int r = 0; r < 4; ++r)
        lds[w * 256 + (q * 4 + r) * 16 + i] = acc[r];
    __syncthreads();

    {
        const int m  = t >> 4;     // 0..15 (batch row)
        const int i2 = t & 15;     // 0..15 (tile col)
        const float v = lds[0 * 256 + t] + lds[1 * 256 + t]
                      + lds[2 * 256 + t] + lds[3 * 256 + t];
        const int n  = nb + i2;
        const float sc = is4 ? 1.f : s8[n - N4];
        const int d  = fwd[n];
        atomicAdd(&out[(size_t)m * NT + d], v * sc);
    }
}

// ---------------------------------------------------------------------------
extern "C" void kernel_launch(void* const* d_in, const int* in_sizes, int n_in,
                              void* d_out, int out_size, void* d_ws, size_t ws_size,
                              hipStream_t stream) {
    const float* x        = (const float*)d_in[0];
    const int*   w_int4   = (const int*)  d_in[1];
    const float* s_int4   = (const float*)d_in[2];
    const int*   w_uint8  = (const int*)  d_in[3];
    const float* s_int8   = (const float*)d_in[4];
    const float* awq      = (const float*)d_in[5];
    const float* bias     = (const float*)d_in[6];
    const int*   inv_perm = (const int*)  d_in[7];
    // d_in[8] = group_size (==128), compile-time constant here

    char* ws = (char*)d_ws;
    short* x2bf       = (short*)ws;                                  // 256 KB
    int*   fwd        = (int*)(ws + 256 * 1024);                     //  32 KB
    unsigned int* p4  = (unsigned int*)(ws + 512 * 1024);            //  24 MiB
    unsigned int* p8  = (unsigned int*)(ws + 512 * 1024
                                        + (size_t)P4_DWORDS * 4);    //  16 MiB

    prep_kernel<<<(16 * K) / 256, 256, 0, stream>>>(x, awq, inv_perm, bias,
                                                    x2bf, fwd, (float*)d_out);
    repack_kernel<<<(P4_DWORDS + P8_DWORDS) / 256, 256, 0, stream>>>(
        w_int4, w_uint8, p4, p8);
    qgemv_kernel<<<(NT / 16) * 2, 256, 0, stream>>>(x2bf, p4, s_int4,
                                                    p8, s_int8, fwd,
                                                    (float*)d_out);
}

// Round 8
// 330.612 us; speedup vs baseline: 1.0734x; 1.0734x over previous
//
#include <hip/hip_runtime.h>
#include <hip/hip_bf16.h>

// Problem constants (match reference file)
constexpr int K    = 8192;
constexpr int N4   = 6144;    // int4 rows
constexpr int N8   = 2048;    // uint8 rows
constexpr int NT   = N4 + N8; // 8192 output columns
constexpr int NG   = K / 128; // 64 groups per int4 row
constexpr int KS   = 4096;    // K per split (split-K x2)

typedef short  short8  __attribute__((ext_vector_type(8)));
typedef float  floatx4 __attribute__((ext_vector_type(4)));
typedef int    intx4   __attribute__((ext_vector_type(4)));  // clang vector:
// __builtin_nontemporal_load accepts this (HIP's int4 struct is rejected).

__device__ inline short f2bf(float f) {
    __hip_bfloat16 h = __float2bfloat16(f);   // RNE
    return __builtin_bit_cast(short, h);
}

// ---------------------------------------------------------------------------
// Prep: x2bf = bf16(x/awq) stored in MFMA A-fragment order:
//   x2bf[c*512 + lane*8 + j] = X[m = lane&15][k = c*32 + (lane>>4)*8 + j]
// Also: fwd = inverse of inv_perm, and out pre-filled with bias (the GEMV
// kernel accumulates into out with atomics; bias folds in for free here).
// ---------------------------------------------------------------------------
__global__ void prep_kernel(const float* __restrict__ x,
                            const float* __restrict__ awq,
                            const int*   __restrict__ inv_perm,
                            const float* __restrict__ bias,
                            short* __restrict__ x2bf,
                            int*   __restrict__ fwd,
                            float* __restrict__ out) {
    const int tid  = blockIdx.x * blockDim.x + threadIdx.x;   // 0..131071
    const int c    = tid >> 9;
    const int rem  = tid & 511;
    const int lane = rem >> 3;
    const int j    = rem & 7;
    const int m    = lane & 15;
    const int k    = c * 32 + (lane >> 4) * 8 + j;
    x2bf[tid] = f2bf(x[m * K + k] / awq[k]);
    if (tid < NT) fwd[inv_perm[tid]] = tid;
    out[tid] = bias[tid & (NT - 1)];          // out = bias, pre-perm indexed
}

// ---------------------------------------------------------------------------
// Split-K x2 MFMA GEMV — round-3 structure (best verified), ONE change:
// weight loads are NON-TEMPORAL (`nt`). Theory: rounds 0/3/4/6 all read the
// 268 MB int32-stored weights at ~2.7 TB/s regardless of access structure
// (scattered / LDS-staged sequential / nibble-packed) with neither HBM
// (19%) nor L3 individually saturated -> shared chokepoint = per-XCD L2
// miss/fill path (~2.2 lines/cy/XCD at the observed rate). Weights are
// strictly read-once, so `nt` (streaming, minimal L2 allocation) targets
// exactly that path. x2bf / scales / fwd stay cached (reused across blocks).
//   int4 rows : wf = w*s - 8s      (group scale s, one per 4 chunks)
//   uint8 rows: wf = w - 128       (exact in bf16; s8 applied in epilogue;
//               algebraic merge of hi/lo nibbles + 8*s*sum_x correction)
// Block = 4 waves = 16-row tile x half of K; 1024 blocks = 4 waves/SIMD.
// 8 groups of 4 chunks, 2-stage A/B register pipeline, sched_barrier pins
// (round-1 failure mode guard: keeps 12 16B loads in flight per stage).
// Epilogue: 4KB LDS cross-wave reduce + s8/perm + atomicAdd (bias seeded).
// ---------------------------------------------------------------------------
__global__ __launch_bounds__(256, 4)
void qgemv_kernel(const short* __restrict__ xf,
                  const int*   __restrict__ w4,
                  const float* __restrict__ s4,
                  const int*   __restrict__ w8,
                  const float* __restrict__ s8,
                  const int*   __restrict__ fwd,
                  float* __restrict__ out) {
    __shared__ float lds[4 * 256];

    const int t     = threadIdx.x;
    const int lane  = t & 63;
    const int w     = t >> 6;              // wave 0..3
    const int tile  = blockIdx.x >> 1;
    const int split = blockIdx.x & 1;
    const int nb    = tile * 16;           // tile base row
    const int i     = lane & 15;
    const int q     = lane >> 4;
    const int row   = nb + i;              // this lane's weight row

    const bool is4  = (nb < N4);
    const int kbase = split * KS + w * 1024;
    const int*   wp = (is4 ? (w4 + (size_t)row * K)
                           : (w8 + (size_t)(row - N4) * K))
                      + kbase + q * 8;                       // + chunk*32 later
    const short* xw = xf + (size_t)(kbase >> 5) * 512 + lane * 8; // + chunk*512
    const float* sp = is4 ? (s4 + (size_t)row * NG + (kbase >> 7)) : nullptr;

    floatx4 acc = {0.f, 0.f, 0.f, 0.f};

    intx4  wbA[8], wbB[8];
    short8 abA[4], abB[4];
    float  sA = 0.f, sB = 0.f;

    // group = 4 chunks = 128 k (one scale group). 8 groups per wave.
    auto loadg = [&](int g, intx4* wb, short8* ab, float& s) {
        #pragma unroll
        for (int c = 0; c < 4; ++c) {
            const size_t co = (size_t)(g * 4 + c);
            wb[2 * c]     = __builtin_nontemporal_load((const intx4*)(wp + co * 32));
            wb[2 * c + 1] = __builtin_nontemporal_load((const intx4*)(wp + co * 32 + 4));
            ab[c]         = *(const short8*)(xw + co * 512);
        }
        if (is4) s = sp[g];
    };

    auto compg = [&](const intx4* wb, const short8* ab, float s) {
        const float sc = is4 ? s : 1.f;
        const float sb = is4 ? -8.f * s : -128.f;
        #pragma unroll
        for (int c = 0; c < 4; ++c) {
            const intx4 wa = wb[2 * c];
            const intx4 wz = wb[2 * c + 1];
            short8 bf;
            bf[0] = f2bf((float)wa[0] * sc + sb);
            bf[1] = f2bf((float)wa[1] * sc + sb);
            bf[2] = f2bf((float)wa[2] * sc + sb);
            bf[3] = f2bf((float)wa[3] * sc + sb);
            bf[4] = f2bf((float)wz[0] * sc + sb);
            bf[5] = f2bf((float)wz[1] * sc + sb);
            bf[6] = f2bf((float)wz[2] * sc + sb);
            bf[7] = f2bf((float)wz[3] * sc + sb);
            acc = __builtin_amdgcn_mfma_f32_16x16x32_bf16(ab[c], bf, acc, 0, 0, 0);
        }
    };

    // 8 groups, 2-stage manual pipeline (A/B buffers), peeled tail.
    loadg(0, wbA, abA, sA);
    __builtin_amdgcn_sched_barrier(0);
    #pragma unroll 1
    for (int g = 0; g < 6; g += 2) {
        loadg(g + 1, wbB, abB, sB);
        __builtin_amdgcn_sched_barrier(0);
        compg(wbA, abA, sA);              // group g
        loadg(g + 2, wbA, abA, sA);
        __builtin_amdgcn_sched_barrier(0);
        compg(wbB, abB, sB);              // group g+1
    }
    loadg(7, wbB, abB, sB);
    __builtin_amdgcn_sched_barrier(0);
    compg(wbA, abA, sA);                  // group 6
    compg(wbB, abB, sB);                  // group 7

    // ---- cross-wave reduce + fused scale/perm atomic writeout ----
    #pragma unroll
    for (int r = 0; r < 4; ++r)
        lds[w * 256 + (q * 4 + r) * 16 + i] = acc[r];
    __syncthreads();

    {
        const int m  = t >> 4;     // 0..15 (batch row)
        const int i2 = t & 15;     // 0..15 (tile col)
        const float v = lds[0 * 256 + t] + lds[1 * 256 + t]
                      + lds[2 * 256 + t] + lds[3 * 256 + t];
        const int n  = nb + i2;
        const float sc = is4 ? 1.f : s8[n - N4];
        const int d  = fwd[n];
        atomicAdd(&out[(size_t)m * NT + d], v * sc);
    }
}

// ---------------------------------------------------------------------------
extern "C" void kernel_launch(void* const* d_in, const int* in_sizes, int n_in,
                              void* d_out, int out_size, void* d_ws, size_t ws_size,
                              hipStream_t stream) {
    const float* x        = (const float*)d_in[0];
    const int*   w_int4   = (const int*)  d_in[1];
    const float* s_int4   = (const float*)d_in[2];
    const int*   w_uint8  = (const int*)  d_in[3];
    const float* s_int8   = (const float*)d_in[4];
    const float* awq      = (const float*)d_in[5];
    const float* bias     = (const float*)d_in[6];
    const int*   inv_perm = (const int*)  d_in[7];
    // d_in[8] = group_size (==128), compile-time constant here

    short* x2bf = (short*)d_ws;                                       // 256 KB
    int*   fwd  = (int*)((char*)d_ws + (size_t)16 * K * sizeof(short)); // 32 KB

    prep_kernel<<<(16 * K) / 256, 256, 0, stream>>>(x, awq, inv_perm, bias,
                                                    x2bf, fwd, (float*)d_out);
    qgemv_kernel<<<(NT / 16) * 2, 256, 0, stream>>>(x2bf, w_int4, s_int4,
                                                    w_uint8, s_int8, fwd,
                                                    (float*)d_out);
}